// Round 9
// baseline (220.517 us; speedup 1.0000x reference)
//
#include <hip/hip_runtime.h>
#include <math.h>

#define E_   1024
#define H_   16
#define B_   4
#define T_   1024
#define LAMBDA_INIT 0.783605766532f
#define SCALE_Q 0.17677669529663687f

typedef short s16x8 __attribute__((ext_vector_type(8)));
typedef float f32x4 __attribute__((ext_vector_type(4)));

// ushort offset of 16B chunk c in a 64-ushort (128B) swizzled row r
#define SWZ(c, r) ((((c) ^ ((r) & 7)) * 8))

// float -> bf16 raw bits, round-to-nearest-even
__device__ inline ushort f2bf(float x) {
    unsigned u = __builtin_bit_cast(unsigned, x);
    u += 0x7fffu + ((u >> 16) & 1u);
    return (ushort)(u >> 16);
}

// pack two floats -> 2x bf16 in one uint (lo, hi)
__device__ inline uint f2bf2(float lo, float hi) {
#if __has_builtin(__builtin_amdgcn_cvt_pk_bf16_f32)
    typedef __bf16 bf16x2_t __attribute__((ext_vector_type(2)));
    bf16x2_t r = __builtin_amdgcn_cvt_pk_bf16_f32(lo, hi);
    return __builtin_bit_cast(uint, r);
#else
    uint ul = __builtin_bit_cast(uint, lo);
    uint uh = __builtin_bit_cast(uint, hi);
    ul += 0x7fffu + ((ul >> 16) & 1u);
    uh += 0x7fffu + ((uh >> 16) & 1u);
    return __builtin_amdgcn_perm(uh, ul, 0x07060302u);
#endif
}

// async global->LDS, 16 bytes per lane; LDS dest = base + lane*16
__device__ inline void gl_lds16(const ushort* g, ushort* l) {
    __builtin_amdgcn_global_load_lds((const __attribute__((address_space(1))) void*)g,
                                     (__attribute__((address_space(3))) void*)l,
                                     16, 0, 0);
}

// ---------------------------------------------------------------------------
// prep: fp32->bf16 casts for x + 4 weights, plus lambda scalar (one launch).
// ---------------------------------------------------------------------------
__global__ __launch_bounds__(256) void prep(
    const float* __restrict__ x,  const float* __restrict__ Wq,
    const float* __restrict__ Wk, const float* __restrict__ Wv,
    const float* __restrict__ Wo,
    const float* __restrict__ lq1, const float* __restrict__ lk1,
    const float* __restrict__ lq2, const float* __restrict__ lk2,
    ushort* __restrict__ xb, ushort* __restrict__ Wqb, ushort* __restrict__ Wkb,
    ushort* __restrict__ Wvb, ushort* __restrict__ Wob, float* __restrict__ lamp)
{
    const int blk = blockIdx.x;
    const int tid = threadIdx.x;
    if (blk >= 4096) {
        if (tid < 64) {
            float p1 = 0.f, p2 = 0.f;
            if (tid < 32) { p1 = lq1[tid] * lk1[tid]; p2 = lq2[tid] * lk2[tid]; }
            #pragma unroll
            for (int off = 32; off; off >>= 1) {
                p1 += __shfl_xor(p1, off);
                p2 += __shfl_xor(p2, off);
            }
            if (tid == 0) lamp[0] = expf(p1) - expf(p2) + LAMBDA_INIT;
        }
        return;
    }
    const float* in;
    ushort* out;
    int base;
    if (blk < 2048) { in = x; out = xb; base = blk; }
    else {
        int t = blk - 2048, w = t >> 9;
        base = t & 511;
        in  = w == 0 ? Wq  : (w == 1 ? Wk  : (w == 2 ? Wv  : Wo));
        out = w == 0 ? Wqb : (w == 1 ? Wkb : (w == 2 ? Wvb : Wob));
    }
    int i = (base * 256 + tid) * 8;
    float4 a = *(const float4*)&in[i];
    float4 b = *(const float4*)&in[i + 4];
    union { ushort u[8]; uint4 v; } o;
    o.u[0] = f2bf(a.x); o.u[1] = f2bf(a.y); o.u[2] = f2bf(a.z); o.u[3] = f2bf(a.w);
    o.u[4] = f2bf(b.x); o.u[5] = f2bf(b.y); o.u[6] = f2bf(b.z); o.u[7] = f2bf(b.w);
    *(uint4*)&out[i] = o.v;
}

// ---------------------------------------------------------------------------
// Fused QKV projection GEMM v2: ping-pong async staging, 1 barrier/K-iter
// (R8's diff_attn-proven structure). Q/K regions computed TRANSPOSED
// (acc = mfma(b, a)) so each lane holds 4 consecutive output cols ->
// vectorized ushort4 epilogue. V region natural order, written transposed
// into Vt[b][e][t] (lane holds 4 consecutive t).
// ---------------------------------------------------------------------------
__global__ __launch_bounds__(256) void gemm_qkv(
    const ushort* __restrict__ Xb, const ushort* __restrict__ Wqb,
    const ushort* __restrict__ Wkb, const ushort* __restrict__ Wvb,
    ushort* __restrict__ QK, ushort* __restrict__ Vt)
{
    __shared__ ushort As[2][128 * 32];
    __shared__ ushort Ws[2][128 * 32];
    const int tid = threadIdx.x;
    const int wave = tid >> 6, lane = tid & 63;
    const int l15 = lane & 15, quad = lane >> 4;
    const int bm = blockIdx.y * 128;
    const int bng = blockIdx.x * 128;
    const int region = bng >> 10;
    const ushort* W = region == 0 ? Wqb : (region == 1 ? Wkb : Wvb);
    const float scale = region == 0 ? SCALE_Q : 1.0f;
    const int wn = bng & 1023;
    const int lrow = lane >> 2;
    const int lcol = (lane & 3) * 8;

    f32x4 acc[4][4] = {};
    const int wr = wave >> 1, wc = wave & 1;

    // stage k0=0 into buffer 0
    #pragma unroll
    for (int p = 0; p < 2; ++p) {
        int i = wave + 4 * p;
        gl_lds16(&Xb[(size_t)(bm + i * 16 + lrow) * 1024 + lcol], &As[0][i * 512]);
        gl_lds16(&W [(size_t)(wn + i * 16 + lrow) * 1024 + lcol], &Ws[0][i * 512]);
    }
    __syncthreads();

    for (int k0 = 0; k0 < 1024; k0 += 32) {
        const int cur = (k0 >> 5) & 1, nxt = cur ^ 1;
        if (k0 + 32 < 1024) {
            #pragma unroll
            for (int p = 0; p < 2; ++p) {
                int i = wave + 4 * p;
                gl_lds16(&Xb[(size_t)(bm + i * 16 + lrow) * 1024 + k0 + 32 + lcol], &As[nxt][i * 512]);
                gl_lds16(&W [(size_t)(wn + i * 16 + lrow) * 1024 + k0 + 32 + lcol], &Ws[nxt][i * 512]);
            }
        }
        s16x8 a[4], b[4];
        #pragma unroll
        for (int i = 0; i < 4; ++i)
            a[i] = *(const s16x8*)&As[cur][(wr * 64 + i * 16 + l15) * 32 + quad * 8];
        #pragma unroll
        for (int j = 0; j < 4; ++j)
            b[j] = *(const s16x8*)&Ws[cur][(wc * 64 + j * 16 + l15) * 32 + quad * 8];
        if (region < 2) {
            // transposed accumulate: acc[i][j] = C^T tile (rows = W-cols)
            #pragma unroll
            for (int i = 0; i < 4; ++i)
                #pragma unroll
                for (int j = 0; j < 4; ++j)
                    acc[i][j] = __builtin_amdgcn_mfma_f32_16x16x32_bf16(b[j], a[i], acc[i][j], 0, 0, 0);
        } else {
            #pragma unroll
            for (int i = 0; i < 4; ++i)
                #pragma unroll
                for (int j = 0; j < 4; ++j)
                    acc[i][j] = __builtin_amdgcn_mfma_f32_16x16x32_bf16(a[i], b[j], acc[i][j], 0, 0, 0);
        }
        __syncthreads();   // one barrier: drains prefetch DMA, releases cur
    }

    if (region < 2) {
        // lane holds: X-row = l15 (within tile i), 4 consecutive cols quad*4+r
        #pragma unroll
        for (int i = 0; i < 4; ++i) {
            int row = bm + wr * 64 + i * 16 + l15;
            #pragma unroll
            for (int j = 0; j < 4; ++j) {
                int col = region * 1024 + wn + wc * 64 + j * 16 + quad * 4;
                ushort4 o;
                o.x = f2bf(acc[i][j][0] * scale); o.y = f2bf(acc[i][j][1] * scale);
                o.z = f2bf(acc[i][j][2] * scale); o.w = f2bf(acc[i][j][3] * scale);
                *(ushort4*)&QK[(size_t)row * 2048 + col] = o;
            }
        }
    } else {
        // V: write transposed, Vt[b][e][t]; lane holds 4 consecutive t per (i,j)
        const int bb = bm >> 10;
        const int t0 = (bm & 1023) + wr * 64 + quad * 4;
        #pragma unroll
        for (int i = 0; i < 4; ++i)
            #pragma unroll
            for (int j = 0; j < 4; ++j) {
                int e = wn + wc * 64 + j * 16 + l15;
                ushort4 o;
                o.x = f2bf(acc[i][j][0]); o.y = f2bf(acc[i][j][1]);
                o.z = f2bf(acc[i][j][2]); o.w = f2bf(acc[i][j][3]);
                *(ushort4*)&Vt[((size_t)bb * E_ + e) * T_ + t0 + i * 16] = o;
            }
    }
}

// ---------------------------------------------------------------------------
// Output GEMM v2: ping-pong staging, 1 barrier/iter, transposed accumulate
// -> float4 epilogue. C_f32[4096][1024] = Ab @ Wo.T (BM=64, BN=128).
// ---------------------------------------------------------------------------
__global__ __launch_bounds__(256) void gemm_out(
    const ushort* __restrict__ Ab, const ushort* __restrict__ Wob,
    float* __restrict__ C)
{
    __shared__ ushort As[2][64 * 32];
    __shared__ ushort Ws[2][128 * 32];
    const int tid = threadIdx.x;
    const int wave = tid >> 6, lane = tid & 63;
    const int l15 = lane & 15, quad = lane >> 4;
    const int bm = blockIdx.y * 64;
    const int bn = blockIdx.x * 128;
    const int lrow = lane >> 2;
    const int lcol = (lane & 3) * 8;

    f32x4 acc[2][4] = {};
    const int wr = wave >> 1, wc = wave & 1;

    gl_lds16(&Ab[(size_t)(bm + wave * 16 + lrow) * 1024 + lcol], &As[0][wave * 512]);
    #pragma unroll
    for (int p = 0; p < 2; ++p) {
        int i = wave + 4 * p;
        gl_lds16(&Wob[(size_t)(bn + i * 16 + lrow) * 1024 + lcol], &Ws[0][i * 512]);
    }
    __syncthreads();

    for (int k0 = 0; k0 < 1024; k0 += 32) {
        const int cur = (k0 >> 5) & 1, nxt = cur ^ 1;
        if (k0 + 32 < 1024) {
            gl_lds16(&Ab[(size_t)(bm + wave * 16 + lrow) * 1024 + k0 + 32 + lcol], &As[nxt][wave * 512]);
            #pragma unroll
            for (int p = 0; p < 2; ++p) {
                int i = wave + 4 * p;
                gl_lds16(&Wob[(size_t)(bn + i * 16 + lrow) * 1024 + k0 + 32 + lcol], &Ws[nxt][i * 512]);
            }
        }
        s16x8 a[2], b[4];
        #pragma unroll
        for (int i = 0; i < 2; ++i)
            a[i] = *(const s16x8*)&As[cur][(wr * 32 + i * 16 + l15) * 32 + quad * 8];
        #pragma unroll
        for (int j = 0; j < 4; ++j)
            b[j] = *(const s16x8*)&Ws[cur][(wc * 64 + j * 16 + l15) * 32 + quad * 8];
        #pragma unroll
        for (int i = 0; i < 2; ++i)
            #pragma unroll
            for (int j = 0; j < 4; ++j)
                acc[i][j] = __builtin_amdgcn_mfma_f32_16x16x32_bf16(b[j], a[i], acc[i][j], 0, 0, 0);
        __syncthreads();
    }

    // lane holds: A-row = l15 (within tile i), 4 consecutive cols quad*4+r
    #pragma unroll
    for (int i = 0; i < 2; ++i) {
        int row = bm + wr * 32 + i * 16 + l15;
        #pragma unroll
        for (int j = 0; j < 4; ++j) {
            int col = bn + wc * 64 + j * 16 + quad * 4;
            float4 o;
            o.x = acc[i][j][0]; o.y = acc[i][j][1];
            o.z = acc[i][j][2]; o.w = acc[i][j][3];
            *(float4*)&C[(size_t)row * 1024 + col] = o;
        }
    }
}

// ---------------------------------------------------------------------------
// Differential attention v6 (unchanged from R8, best so far): ping-pong async
// staging, 1 barrier/kt, XOR-swizzled packed LDS, per-wave Pt round-trip.
// ---------------------------------------------------------------------------
__global__ __launch_bounds__(256, 4) void diff_attn(
    const ushort* __restrict__ QK, const ushort* __restrict__ Vt,
    const float* __restrict__ g, const float* __restrict__ lamp,
    ushort* __restrict__ O)
{
    __shared__ __align__(16) ushort Ks[2][4096];   // 16 KB
    __shared__ __align__(16) ushort Vts[2][4096];  // 16 KB
    __shared__ __align__(16) ushort Pt[4][1024];   //  8 KB

    const int tid  = threadIdx.x;
    const int lane = tid & 63;
    const int wave = tid >> 6;
    const int l15  = lane & 15;
    const int quad = lane >> 4;

    const int blk = blockIdx.x;
    const int bh = blk & 63;           // same-head blocks share blk%8 -> same XCD
    const int qt = blk >> 6;
    const int b  = bh >> 4;
    const int h  = bh & 15;
    const int q0 = qt * 64;
    const int hoff = h * 64;
    const size_t rowbase = (size_t)b * T_;

    const ushort* Qg = QK;
    const ushort* Kg = QK + 1024;
    const size_t vtbase = ((size_t)b * E_ + hoff) * T_;

    const int lr  = lane >> 3;
    const int jsw = ((lane & 7) ^ lr) * 8;

    const size_t qrow = (rowbase + q0 + wave * 16 + l15) * 2048 + hoff;
    s16x8 aq0 = *(const s16x8*)&Qg[qrow + quad * 8];
    s16x8 aq1 = *(const s16x8*)&Qg[qrow + 32 + quad * 8];

    const int kaoff0 = l15 * 64 + SWZ(quad,     l15);
    const int kaoff1 = l15 * 64 + SWZ(4 + quad, l15);
    ushort* myPt = &Pt[wave][0];

    const f32x4 zf = {0.f, 0.f, 0.f, 0.f};
    f32x4 o0[4] = {zf, zf, zf, zf};
    f32x4 o1[4] = {zf, zf, zf, zf};
    float lsum0 = 0.f, lsum1 = 0.f;

    #pragma unroll
    for (int p = 0; p < 2; ++p) {
        int r = wave * 16 + p * 8;
        gl_lds16(&Kg[(rowbase + r + lr) * 2048 + hoff + jsw], &Ks[0][r * 64]);
        gl_lds16(&Vt[vtbase + (size_t)(r + lr) * T_ + jsw],   &Vts[0][r * 64]);
    }
    __syncthreads();

    for (int kt = 0; kt < 16; ++kt) {
        const int cur = kt & 1;
        const int nxt = cur ^ 1;
        {
            const int ktn = (kt + 1) & 15;
            #pragma unroll
            for (int p = 0; p < 2; ++p) {
                int r = wave * 16 + p * 8;
                gl_lds16(&Kg[(rowbase + ktn * 64 + r + lr) * 2048 + hoff + jsw],
                         &Ks[nxt][r * 64]);
                gl_lds16(&Vt[vtbase + (size_t)(r + lr) * T_ + ktn * 64 + jsw],
                         &Vts[nxt][r * 64]);
            }
        }

        s16x8 va[4][2];
        #pragma unroll
        for (int jt = 0; jt < 4; ++jt) {
            va[jt][0] = *(const s16x8*)&Vts[cur][jt * 1024 + kaoff0];
            va[jt][1] = *(const s16x8*)&Vts[cur][jt * 1024 + kaoff1];
        }

        // ---- comp 0 ----
        {
            f32x4 S[4];
            #pragma unroll
            for (int jk = 0; jk < 4; ++jk) {
                s16x8 ka = *(const s16x8*)&Ks[cur][jk * 1024 + kaoff0];
                S[jk] = __builtin_amdgcn_mfma_f32_16x16x32_bf16(ka, aq0, zf, 0, 0, 0);
            }
            #pragma unroll
            for (int jk = 0; jk < 4; ++jk) {
                float e0 = __expf(S[jk][0]), e1 = __expf(S[jk][1]);
                float e2 = __expf(S[jk][2]), e3 = __expf(S[jk][3]);
                lsum0 += (e0 + e1) + (e2 + e3);
                uint2 pk; pk.x = f2bf2(e0, e1); pk.y = f2bf2(e2, e3);
                *(uint2*)&myPt[l15 * 64 + SWZ(2 * jk + (quad >> 1), l15) + (quad & 1) * 4] = pk;
            }
            #pragma unroll
            for (int h2 = 0; h2 < 2; ++h2) {
                s16x8 pf = *(const s16x8*)&myPt[h2 ? kaoff1 : kaoff0];
                #pragma unroll
                for (int jt = 0; jt < 4; ++jt)
                    o0[jt] = __builtin_amdgcn_mfma_f32_16x16x32_bf16(va[jt][h2], pf, o0[jt], 0, 0, 0);
            }
        }
        // ---- comp 1 ----
        {
            f32x4 S[4];
            #pragma unroll
            for (int jk = 0; jk < 4; ++jk) {
                s16x8 ka = *(const s16x8*)&Ks[cur][jk * 1024 + kaoff1];
                S[jk] = __builtin_amdgcn_mfma_f32_16x16x32_bf16(ka, aq1, zf, 0, 0, 0);
            }
            #pragma unroll
            for (int jk = 0; jk < 4; ++jk) {
                float e0 = __expf(S[jk][0]), e1 = __expf(S[jk][1]);
                float e2 = __expf(S[jk][2]), e3 = __expf(S[jk][3]);
                lsum1 += (e0 + e1) + (e2 + e3);
                uint2 pk; pk.x = f2bf2(e0, e1); pk.y = f2bf2(e2, e3);
                *(uint2*)&myPt[l15 * 64 + SWZ(2 * jk + (quad >> 1), l15) + (quad & 1) * 4] = pk;
            }
            #pragma unroll
            for (int h2 = 0; h2 < 2; ++h2) {
                s16x8 pf = *(const s16x8*)&myPt[h2 ? kaoff1 : kaoff0];
                #pragma unroll
                for (int jt = 0; jt < 4; ++jt)
                    o1[jt] = __builtin_amdgcn_mfma_f32_16x16x32_bf16(va[jt][h2], pf, o1[jt], 0, 0, 0);
            }
        }
        __syncthreads();
    }

    lsum0 += __shfl_xor(lsum0, 16); lsum0 += __shfl_xor(lsum0, 32);
    lsum1 += __shfl_xor(lsum1, 16); lsum1 += __shfl_xor(lsum1, 32);

    const float lam = lamp[0];
    const float fin = 1.f - LAMBDA_INIT;
    float i0 = 1.f / lsum0;
    float i1 = lam / lsum1;
    float val[4][4];
    float ssq = 0.f;
    #pragma unroll
    for (int jt = 0; jt < 4; ++jt)
        #pragma unroll
        for (int r = 0; r < 4; ++r) {
            float v = o0[jt][r] * i0 - o1[jt][r] * i1;
            val[jt][r] = v;
            ssq += v * v;
        }
    ssq += __shfl_xor(ssq, 16);
    ssq += __shfl_xor(ssq, 32);
    float sc = rsqrtf(ssq * (1.f / 64.f) + 1e-5f) * fin;
    size_t rowoff = (rowbase + q0 + wave * 16 + l15) * 1024 + hoff;
    #pragma unroll
    for (int jt = 0; jt < 4; ++jt) {
        float4 gv = *(const float4*)&g[jt * 16 + quad * 4];
        uint p01 = f2bf2(val[jt][0] * sc * gv.x, val[jt][1] * sc * gv.y);
        uint p23 = f2bf2(val[jt][2] * sc * gv.z, val[jt][3] * sc * gv.w);
        *(uint*)&O[rowoff + jt * 16 + quad * 4 + 0] = p01;
        *(uint*)&O[rowoff + jt * 16 + quad * 4 + 2] = p23;
    }
}

// ---------------------------------------------------------------------------
extern "C" void kernel_launch(void* const* d_in, const int* in_sizes, int n_in,
                              void* d_out, int out_size, void* d_ws, size_t ws_size,
                              hipStream_t stream)
{
    const float* x   = (const float*)d_in[0];
    const float* Wq  = (const float*)d_in[1];
    const float* Wk  = (const float*)d_in[2];
    const float* Wv  = (const float*)d_in[3];
    const float* Wo  = (const float*)d_in[4];
    const float* lq1 = (const float*)d_in[5];
    const float* lk1 = (const float*)d_in[6];
    const float* lq2 = (const float*)d_in[7];
    const float* lk2 = (const float*)d_in[8];
    const float* g   = (const float*)d_in[9];
    float* out = (float*)d_out;

    const int M = B_ * T_;                 // 4096
    const size_t ME = (size_t)M * E_;      // 4M elems
    const size_t EE = (size_t)E_ * E_;     // 1M elems
    ushort* xb  = (ushort*)d_ws;           // x bf16; later reused as Ab
    ushort* Wqb = xb  + ME;
    ushort* Wkb = Wqb + EE;
    ushort* Wvb = Wkb + EE;
    ushort* Wob = Wvb + EE;
    ushort* QK  = Wob + EE;                // [4096][2048] bf16
    ushort* Vtb = QK + (size_t)M * 2048;   // [4][1024][1024] bf16 (e-major)
    float*  lamp = (float*)(Vtb + ME);
    ushort* Ab  = xb;                      // aliases xb (dead after gemm_qkv)

    prep<<<4097, 256, 0, stream>>>(x, Wq, Wk, Wv, Wo, lq1, lk1, lq2, lk2,
                                   xb, Wqb, Wkb, Wvb, Wob, lamp);
    gemm_qkv<<<dim3(24, 32), 256, 0, stream>>>(xb, Wqb, Wkb, Wvb, QK, Vtb);
    diff_attn<<<B_ * H_ * (T_ / 64), 256, 0, stream>>>(QK, Vtb, g, lamp, Ab);
    gemm_out<<<dim3(8, 64), 256, 0, stream>>>(Ab, Wob, out);
}

// Round 10
// 201.703 us; speedup vs baseline: 1.0933x; 1.0933x over previous
//
#include <hip/hip_runtime.h>
#include <math.h>

#define E_   1024
#define H_   16
#define B_   4
#define T_   1024
#define LAMBDA_INIT 0.783605766532f
// D^-1/2 * log2(e): Q pre-scaled so softmax exp becomes raw v_exp_f32 (2^x)
#define SCALE_QL2E 0.25503486f

typedef short s16x8 __attribute__((ext_vector_type(8)));
typedef float f32x4 __attribute__((ext_vector_type(4)));

// ushort offset of 16B chunk c in a 64-ushort (128B) swizzled row r
#define SWZ(c, r) ((((c) ^ ((r) & 7)) * 8))

// float -> bf16 raw bits, round-to-nearest-even
__device__ inline ushort f2bf(float x) {
    unsigned u = __builtin_bit_cast(unsigned, x);
    u += 0x7fffu + ((u >> 16) & 1u);
    return (ushort)(u >> 16);
}

// pack two floats -> 2x bf16 in one uint (lo, hi)
__device__ inline uint f2bf2(float lo, float hi) {
#if __has_builtin(__builtin_amdgcn_cvt_pk_bf16_f32)
    typedef __bf16 bf16x2_t __attribute__((ext_vector_type(2)));
    bf16x2_t r = __builtin_amdgcn_cvt_pk_bf16_f32(lo, hi);
    return __builtin_bit_cast(uint, r);
#else
    uint ul = __builtin_bit_cast(uint, lo);
    uint uh = __builtin_bit_cast(uint, hi);
    ul += 0x7fffu + ((ul >> 16) & 1u);
    uh += 0x7fffu + ((uh >> 16) & 1u);
    return __builtin_amdgcn_perm(uh, ul, 0x07060302u);
#endif
}

// raw 2^x (v_exp_f32, no preceding v_mul)
__device__ inline float exp2fast(float x) {
#if __has_builtin(__builtin_amdgcn_exp2f)
    return __builtin_amdgcn_exp2f(x);
#else
    return exp2f(x);
#endif
}

// async global->LDS, 16 bytes per lane; LDS dest = base + lane*16
__device__ inline void gl_lds16(const ushort* g, ushort* l) {
    __builtin_amdgcn_global_load_lds((const __attribute__((address_space(1))) void*)g,
                                     (__attribute__((address_space(3))) void*)l,
                                     16, 0, 0);
}

// ---------------------------------------------------------------------------
// prep: fp32->bf16 casts for x + 4 weights, plus lambda scalar (one launch).
// ---------------------------------------------------------------------------
__global__ __launch_bounds__(256) void prep(
    const float* __restrict__ x,  const float* __restrict__ Wq,
    const float* __restrict__ Wk, const float* __restrict__ Wv,
    const float* __restrict__ Wo,
    const float* __restrict__ lq1, const float* __restrict__ lk1,
    const float* __restrict__ lq2, const float* __restrict__ lk2,
    ushort* __restrict__ xb, ushort* __restrict__ Wqb, ushort* __restrict__ Wkb,
    ushort* __restrict__ Wvb, ushort* __restrict__ Wob, float* __restrict__ lamp)
{
    const int blk = blockIdx.x;
    const int tid = threadIdx.x;
    if (blk >= 4096) {
        if (tid < 64) {
            float p1 = 0.f, p2 = 0.f;
            if (tid < 32) { p1 = lq1[tid] * lk1[tid]; p2 = lq2[tid] * lk2[tid]; }
            #pragma unroll
            for (int off = 32; off; off >>= 1) {
                p1 += __shfl_xor(p1, off);
                p2 += __shfl_xor(p2, off);
            }
            if (tid == 0) lamp[0] = expf(p1) - expf(p2) + LAMBDA_INIT;
        }
        return;
    }
    const float* in;
    ushort* out;
    int base;
    if (blk < 2048) { in = x; out = xb; base = blk; }
    else {
        int t = blk - 2048, w = t >> 9;
        base = t & 511;
        in  = w == 0 ? Wq  : (w == 1 ? Wk  : (w == 2 ? Wv  : Wo));
        out = w == 0 ? Wqb : (w == 1 ? Wkb : (w == 2 ? Wvb : Wob));
    }
    int i = (base * 256 + tid) * 8;
    float4 a = *(const float4*)&in[i];
    float4 b = *(const float4*)&in[i + 4];
    union { ushort u[8]; uint4 v; } o;
    o.u[0] = f2bf(a.x); o.u[1] = f2bf(a.y); o.u[2] = f2bf(a.z); o.u[3] = f2bf(a.w);
    o.u[4] = f2bf(b.x); o.u[5] = f2bf(b.y); o.u[6] = f2bf(b.z); o.u[7] = f2bf(b.w);
    *(uint4*)&out[i] = o.v;
}

// ---------------------------------------------------------------------------
// Fused QKV projection GEMM (R8 2-barrier loop). Q/K regions accumulate
// TRANSPOSED (acc = mfma(b, a)) -> each lane holds 4 consecutive output
// cols -> ushort4 epilogue. Q carries D^-1/2*log2(e) (exp2 softmax).
// V region natural order, written transposed into Vt[b][e][t].
// ---------------------------------------------------------------------------
__global__ __launch_bounds__(256) void gemm_qkv(
    const ushort* __restrict__ Xb, const ushort* __restrict__ Wqb,
    const ushort* __restrict__ Wkb, const ushort* __restrict__ Wvb,
    ushort* __restrict__ QK, ushort* __restrict__ Vt)
{
    __shared__ ushort As[128 * 32];
    __shared__ ushort Ws[128 * 32];
    const int tid = threadIdx.x;
    const int wave = tid >> 6, lane = tid & 63;
    const int l15 = lane & 15, quad = lane >> 4;
    const int bm = blockIdx.y * 128;
    const int bng = blockIdx.x * 128;
    const int region = bng >> 10;
    const ushort* W = region == 0 ? Wqb : (region == 1 ? Wkb : Wvb);
    const float scale = region == 0 ? SCALE_QL2E : 1.0f;
    const int wn = bng & 1023;
    const int lrow = lane >> 2;
    const int lcol = (lane & 3) * 8;

    f32x4 acc[4][4] = {};
    const int wr = wave >> 1, wc = wave & 1;

    for (int k0 = 0; k0 < 1024; k0 += 32) {
        #pragma unroll
        for (int p = 0; p < 2; ++p) {
            int i = wave + 4 * p;
            gl_lds16(&Xb[(size_t)(bm + i * 16 + lrow) * 1024 + k0 + lcol], &As[i * 512]);
            gl_lds16(&W [(size_t)(wn + i * 16 + lrow) * 1024 + k0 + lcol], &Ws[i * 512]);
        }
        __syncthreads();
        s16x8 a[4], b[4];
        #pragma unroll
        for (int i = 0; i < 4; ++i)
            a[i] = *(const s16x8*)&As[(wr * 64 + i * 16 + l15) * 32 + quad * 8];
        #pragma unroll
        for (int j = 0; j < 4; ++j)
            b[j] = *(const s16x8*)&Ws[(wc * 64 + j * 16 + l15) * 32 + quad * 8];
        if (region < 2) {
            #pragma unroll
            for (int i = 0; i < 4; ++i)
                #pragma unroll
                for (int j = 0; j < 4; ++j)
                    acc[i][j] = __builtin_amdgcn_mfma_f32_16x16x32_bf16(b[j], a[i], acc[i][j], 0, 0, 0);
        } else {
            #pragma unroll
            for (int i = 0; i < 4; ++i)
                #pragma unroll
                for (int j = 0; j < 4; ++j)
                    acc[i][j] = __builtin_amdgcn_mfma_f32_16x16x32_bf16(a[i], b[j], acc[i][j], 0, 0, 0);
        }
        __syncthreads();
    }

    if (region < 2) {
        // lane holds: X-row = l15 (tile i), 4 consecutive cols quad*4+r (tile j)
        #pragma unroll
        for (int i = 0; i < 4; ++i) {
            int row = bm + wr * 64 + i * 16 + l15;
            #pragma unroll
            for (int j = 0; j < 4; ++j) {
                int col = region * 1024 + wn + wc * 64 + j * 16 + quad * 4;
                ushort4 o;
                o.x = f2bf(acc[i][j][0] * scale); o.y = f2bf(acc[i][j][1] * scale);
                o.z = f2bf(acc[i][j][2] * scale); o.w = f2bf(acc[i][j][3] * scale);
                *(ushort4*)&QK[(size_t)row * 2048 + col] = o;
            }
        }
    } else {
        // V: write transposed, Vt[b][e][t]; lane holds 4 consecutive t per (i,j)
        const int bb = bm >> 10;
        const int t0 = (bm & 1023) + wr * 64 + quad * 4;
        #pragma unroll
        for (int i = 0; i < 4; ++i)
            #pragma unroll
            for (int j = 0; j < 4; ++j) {
                int e = wn + wc * 64 + j * 16 + l15;
                ushort4 o;
                o.x = f2bf(acc[i][j][0]); o.y = f2bf(acc[i][j][1]);
                o.z = f2bf(acc[i][j][2]); o.w = f2bf(acc[i][j][3]);
                *(ushort4*)&Vt[((size_t)bb * E_ + e) * T_ + t0 + i * 16] = o;
            }
    }
}

// ---------------------------------------------------------------------------
// Output GEMM (R8 2-barrier loop) + transposed accumulate -> float4 epilogue.
// C_f32[4096][1024] = Ab @ Wo.T (BM=64, BN=128).
// ---------------------------------------------------------------------------
__global__ __launch_bounds__(256) void gemm_out(
    const ushort* __restrict__ Ab, const ushort* __restrict__ Wob,
    float* __restrict__ C)
{
    __shared__ ushort As[64 * 32];
    __shared__ ushort Ws[128 * 32];
    const int tid = threadIdx.x;
    const int wave = tid >> 6, lane = tid & 63;
    const int l15 = lane & 15, quad = lane >> 4;
    const int bm = blockIdx.y * 64;
    const int bn = blockIdx.x * 128;
    const int lrow = lane >> 2;
    const int lcol = (lane & 3) * 8;

    f32x4 acc[2][4] = {};
    const int wr = wave >> 1, wc = wave & 1;

    for (int k0 = 0; k0 < 1024; k0 += 32) {
        gl_lds16(&Ab[(size_t)(bm + wave * 16 + lrow) * 1024 + k0 + lcol], &As[wave * 512]);
        #pragma unroll
        for (int p = 0; p < 2; ++p) {
            int i = wave + 4 * p;
            gl_lds16(&Wob[(size_t)(bn + i * 16 + lrow) * 1024 + k0 + lcol], &Ws[i * 512]);
        }
        __syncthreads();
        s16x8 a[2], b[4];
        #pragma unroll
        for (int i = 0; i < 2; ++i)
            a[i] = *(const s16x8*)&As[(wr * 32 + i * 16 + l15) * 32 + quad * 8];
        #pragma unroll
        for (int j = 0; j < 4; ++j)
            b[j] = *(const s16x8*)&Ws[(wc * 64 + j * 16 + l15) * 32 + quad * 8];
        #pragma unroll
        for (int i = 0; i < 2; ++i)
            #pragma unroll
            for (int j = 0; j < 4; ++j)
                acc[i][j] = __builtin_amdgcn_mfma_f32_16x16x32_bf16(b[j], a[i], acc[i][j], 0, 0, 0);
        __syncthreads();
    }

    // lane holds: A-row = l15 (tile i), 4 consecutive cols quad*4+r (tile j)
    #pragma unroll
    for (int i = 0; i < 2; ++i) {
        int row = bm + wr * 32 + i * 16 + l15;
        #pragma unroll
        for (int j = 0; j < 4; ++j) {
            int col = bn + wc * 64 + j * 16 + quad * 4;
            float4 o;
            o.x = acc[i][j][0]; o.y = acc[i][j][1];
            o.z = acc[i][j][2]; o.w = acc[i][j][3];
            *(float4*)&C[(size_t)row * 1024 + col] = o;
        }
    }
}

// ---------------------------------------------------------------------------
// Differential attention v6 (R8 structure, best measured): ping-pong async
// staging, 1 barrier/kt, XOR-swizzled packed LDS, per-wave Pt round-trip.
// Only change vs R8: P = exp2(S) raw v_exp_f32 (Q pre-scaled by log2e).
// ---------------------------------------------------------------------------
__global__ __launch_bounds__(256, 4) void diff_attn(
    const ushort* __restrict__ QK, const ushort* __restrict__ Vt,
    const float* __restrict__ g, const float* __restrict__ lamp,
    ushort* __restrict__ O)
{
    __shared__ __align__(16) ushort Ks[2][4096];   // 16 KB
    __shared__ __align__(16) ushort Vts[2][4096];  // 16 KB
    __shared__ __align__(16) ushort Pt[4][1024];   //  8 KB

    const int tid  = threadIdx.x;
    const int lane = tid & 63;
    const int wave = tid >> 6;
    const int l15  = lane & 15;
    const int quad = lane >> 4;

    const int blk = blockIdx.x;
    const int bh = blk & 63;           // same-head blocks share blk%8 -> same XCD
    const int qt = blk >> 6;
    const int b  = bh >> 4;
    const int h  = bh & 15;
    const int q0 = qt * 64;
    const int hoff = h * 64;
    const size_t rowbase = (size_t)b * T_;

    const ushort* Qg = QK;
    const ushort* Kg = QK + 1024;
    const size_t vtbase = ((size_t)b * E_ + hoff) * T_;

    const int lr  = lane >> 3;
    const int jsw = ((lane & 7) ^ lr) * 8;

    const size_t qrow = (rowbase + q0 + wave * 16 + l15) * 2048 + hoff;
    s16x8 aq0 = *(const s16x8*)&Qg[qrow + quad * 8];
    s16x8 aq1 = *(const s16x8*)&Qg[qrow + 32 + quad * 8];

    const int kaoff0 = l15 * 64 + SWZ(quad,     l15);
    const int kaoff1 = l15 * 64 + SWZ(4 + quad, l15);
    ushort* myPt = &Pt[wave][0];

    const f32x4 zf = {0.f, 0.f, 0.f, 0.f};
    f32x4 o0[4] = {zf, zf, zf, zf};
    f32x4 o1[4] = {zf, zf, zf, zf};
    float lsum0 = 0.f, lsum1 = 0.f;

    #pragma unroll
    for (int p = 0; p < 2; ++p) {
        int r = wave * 16 + p * 8;
        gl_lds16(&Kg[(rowbase + r + lr) * 2048 + hoff + jsw], &Ks[0][r * 64]);
        gl_lds16(&Vt[vtbase + (size_t)(r + lr) * T_ + jsw],   &Vts[0][r * 64]);
    }
    __syncthreads();

    for (int kt = 0; kt < 16; ++kt) {
        const int cur = kt & 1;
        const int nxt = cur ^ 1;
        {
            const int ktn = (kt + 1) & 15;
            #pragma unroll
            for (int p = 0; p < 2; ++p) {
                int r = wave * 16 + p * 8;
                gl_lds16(&Kg[(rowbase + ktn * 64 + r + lr) * 2048 + hoff + jsw],
                         &Ks[nxt][r * 64]);
                gl_lds16(&Vt[vtbase + (size_t)(r + lr) * T_ + ktn * 64 + jsw],
                         &Vts[nxt][r * 64]);
            }
        }

        s16x8 va[4][2];
        #pragma unroll
        for (int jt = 0; jt < 4; ++jt) {
            va[jt][0] = *(const s16x8*)&Vts[cur][jt * 1024 + kaoff0];
            va[jt][1] = *(const s16x8*)&Vts[cur][jt * 1024 + kaoff1];
        }

        // ---- comp 0 ----
        {
            f32x4 S[4];
            #pragma unroll
            for (int jk = 0; jk < 4; ++jk) {
                s16x8 ka = *(const s16x8*)&Ks[cur][jk * 1024 + kaoff0];
                S[jk] = __builtin_amdgcn_mfma_f32_16x16x32_bf16(ka, aq0, zf, 0, 0, 0);
            }
            #pragma unroll
            for (int jk = 0; jk < 4; ++jk) {
                float e0 = exp2fast(S[jk][0]), e1 = exp2fast(S[jk][1]);
                float e2 = exp2fast(S[jk][2]), e3 = exp2fast(S[jk][3]);
                lsum0 += (e0 + e1) + (e2 + e3);
                uint2 pk; pk.x = f2bf2(e0, e1); pk.y = f2bf2(e2, e3);
                *(uint2*)&myPt[l15 * 64 + SWZ(2 * jk + (quad >> 1), l15) + (quad & 1) * 4] = pk;
            }
            #pragma unroll
            for (int h2 = 0; h2 < 2; ++h2) {
                s16x8 pf = *(const s16x8*)&myPt[h2 ? kaoff1 : kaoff0];
                #pragma unroll
                for (int jt = 0; jt < 4; ++jt)
                    o0[jt] = __builtin_amdgcn_mfma_f32_16x16x32_bf16(va[jt][h2], pf, o0[jt], 0, 0, 0);
            }
        }
        // ---- comp 1 ----
        {
            f32x4 S[4];
            #pragma unroll
            for (int jk = 0; jk < 4; ++jk) {
                s16x8 ka = *(const s16x8*)&Ks[cur][jk * 1024 + kaoff1];
                S[jk] = __builtin_amdgcn_mfma_f32_16x16x32_bf16(ka, aq1, zf, 0, 0, 0);
            }
            #pragma unroll
            for (int jk = 0; jk < 4; ++jk) {
                float e0 = exp2fast(S[jk][0]), e1 = exp2fast(S[jk][1]);
                float e2 = exp2fast(S[jk][2]), e3 = exp2fast(S[jk][3]);
                lsum1 += (e0 + e1) + (e2 + e3);
                uint2 pk; pk.x = f2bf2(e0, e1); pk.y = f2bf2(e2, e3);
                *(uint2*)&myPt[l15 * 64 + SWZ(2 * jk + (quad >> 1), l15) + (quad & 1) * 4] = pk;
            }
            #pragma unroll
            for (int h2 = 0; h2 < 2; ++h2) {
                s16x8 pf = *(const s16x8*)&myPt[h2 ? kaoff1 : kaoff0];
                #pragma unroll
                for (int jt = 0; jt < 4; ++jt)
                    o1[jt] = __builtin_amdgcn_mfma_f32_16x16x32_bf16(va[jt][h2], pf, o1[jt], 0, 0, 0);
            }
        }
        __syncthreads();
    }

    lsum0 += __shfl_xor(lsum0, 16); lsum0 += __shfl_xor(lsum0, 32);
    lsum1 += __shfl_xor(lsum1, 16); lsum1 += __shfl_xor(lsum1, 32);

    const float lam = lamp[0];
    const float fin = 1.f - LAMBDA_INIT;
    float i0 = 1.f / lsum0;
    float i1 = lam / lsum1;
    float val[4][4];
    float ssq = 0.f;
    #pragma unroll
    for (int jt = 0; jt < 4; ++jt)
        #pragma unroll
        for (int r = 0; r < 4; ++r) {
            float v = o0[jt][r] * i0 - o1[jt][r] * i1;
            val[jt][r] = v;
            ssq += v * v;
        }
    ssq += __shfl_xor(ssq, 16);
    ssq += __shfl_xor(ssq, 32);
    float sc = rsqrtf(ssq * (1.f / 64.f) + 1e-5f) * fin;
    size_t rowoff = (rowbase + q0 + wave * 16 + l15) * 1024 + hoff;
    #pragma unroll
    for (int jt = 0; jt < 4; ++jt) {
        float4 gv = *(const float4*)&g[jt * 16 + quad * 4];
        uint p01 = f2bf2(val[jt][0] * sc * gv.x, val[jt][1] * sc * gv.y);
        uint p23 = f2bf2(val[jt][2] * sc * gv.z, val[jt][3] * sc * gv.w);
        *(uint*)&O[rowoff + jt * 16 + quad * 4 + 0] = p01;
        *(uint*)&O[rowoff + jt * 16 + quad * 4 + 2] = p23;
    }
}

// ---------------------------------------------------------------------------
extern "C" void kernel_launch(void* const* d_in, const int* in_sizes, int n_in,
                              void* d_out, int out_size, void* d_ws, size_t ws_size,
                              hipStream_t stream)
{
    const float* x   = (const float*)d_in[0];
    const float* Wq  = (const float*)d_in[1];
    const float* Wk  = (const float*)d_in[2];
    const float* Wv  = (const float*)d_in[3];
    const float* Wo  = (const float*)d_in[4];
    const float* lq1 = (const float*)d_in[5];
    const float* lk1 = (const float*)d_in[6];
    const float* lq2 = (const float*)d_in[7];
    const float* lk2 = (const float*)d_in[8];
    const float* g   = (const float*)d_in[9];
    float* out = (float*)d_out;

    const int M = B_ * T_;                 // 4096
    const size_t ME = (size_t)M * E_;      // 4M elems
    const size_t EE = (size_t)E_ * E_;     // 1M elems
    ushort* xb  = (ushort*)d_ws;           // x bf16; later reused as Ab
    ushort* Wqb = xb  + ME;
    ushort* Wkb = Wqb + EE;
    ushort* Wvb = Wkb + EE;
    ushort* Wob = Wvb + EE;
    ushort* QK  = Wob + EE;                // [4096][2048] bf16
    ushort* Vtb = QK + (size_t)M * 2048;   // [4][1024][1024] bf16 (e-major)
    float*  lamp = (float*)(Vtb + ME);
    ushort* Ab  = xb;                      // aliases xb (dead after gemm_qkv)

    prep<<<4097, 256, 0, stream>>>(x, Wq, Wk, Wv, Wo, lq1, lk1, lq2, lk2,
                                   xb, Wqb, Wkb, Wvb, Wob, lamp);
    gemm_qkv<<<dim3(24, 32), 256, 0, stream>>>(xb, Wqb, Wkb, Wvb, QK, Vtb);
    diff_attn<<<B_ * H_ * (T_ / 64), 256, 0, stream>>>(QK, Vtb, g, lamp, Ab);
    gemm_out<<<dim3(8, 64), 256, 0, stream>>>(Ab, Wob, out);
}